// Round 1
// baseline (460.008 us; speedup 1.0000x reference)
//
#include <hip/hip_runtime.h>

#define U 128
#define UV 32          // U/4 float4s
#define NSEG 4
#define NPATH 20
#define ROW (NSEG * UV)  // 128 float4 per batch row

// Kernel 1: collapse the 20 (i0,i1,i2,coef) paths into dense W[s2][a][b] (64 floats).
__global__ void build_w_kernel(const float* __restrict__ coef,
                               const int* __restrict__ idx,
                               float* __restrict__ W) {
    int j = threadIdx.x;
    if (j >= 64) return;
    int s2 = j >> 4;
    int a  = (j >> 2) & 3;
    int b  = j & 3;
    float w = 0.0f;
    for (int p = 0; p < NPATH; ++p) {
        int i0 = idx[p * 3 + 0];
        int i1 = idx[p * 3 + 1];
        int i2 = idx[p * 3 + 2];
        if (i0 == a && i1 == b && i2 == s2) w += coef[p];
    }
    W[j] = w;
}

// Kernel 2: one thread per (batch, u-quad). out[s2] = sum_a a0[a] * (sum_b W[s2][a][b] * a1[b])
__global__ __launch_bounds__(256) void tp_main_kernel(const float4* __restrict__ x0,
                                                      const float4* __restrict__ x1,
                                                      const float* __restrict__ W,
                                                      float4* __restrict__ out,
                                                      int total) {
    int t = blockIdx.x * 256 + threadIdx.x;
    if (t >= total) return;
    int b = t >> 5;    // batch index
    int u = t & 31;    // float4 lane within U
    int base = b * ROW + u;

    float4 a[NSEG], c[NSEG];
#pragma unroll
    for (int s = 0; s < NSEG; ++s) a[s] = x0[base + s * UV];
#pragma unroll
    for (int s = 0; s < NSEG; ++s) c[s] = x1[base + s * UV];

#pragma unroll
    for (int s2 = 0; s2 < NSEG; ++s2) {
        float4 acc = make_float4(0.f, 0.f, 0.f, 0.f);
#pragma unroll
        for (int aa = 0; aa < NSEG; ++aa) {
            float4 tv = make_float4(0.f, 0.f, 0.f, 0.f);
#pragma unroll
            for (int bb = 0; bb < NSEG; ++bb) {
                float wv = W[s2 * 16 + aa * 4 + bb];   // wave-uniform -> SGPR
                tv.x = fmaf(wv, c[bb].x, tv.x);
                tv.y = fmaf(wv, c[bb].y, tv.y);
                tv.z = fmaf(wv, c[bb].z, tv.z);
                tv.w = fmaf(wv, c[bb].w, tv.w);
            }
            acc.x = fmaf(a[aa].x, tv.x, acc.x);
            acc.y = fmaf(a[aa].y, tv.y, acc.y);
            acc.z = fmaf(a[aa].z, tv.z, acc.z);
            acc.w = fmaf(a[aa].w, tv.w, acc.w);
        }
        out[base + s2 * UV] = acc;
    }
}

extern "C" void kernel_launch(void* const* d_in, const int* in_sizes, int n_in,
                              void* d_out, int out_size, void* d_ws, size_t ws_size,
                              hipStream_t stream) {
    const float* x0   = (const float*)d_in[0];
    const float* x1   = (const float*)d_in[1];
    const float* coef = (const float*)d_in[2];
    const int*   idx  = (const int*)d_in[3];
    float* W = (float*)d_ws;

    int batch = in_sizes[0] / (NSEG * U);
    int total = batch * UV;

    build_w_kernel<<<1, 64, 0, stream>>>(coef, idx, W);
    tp_main_kernel<<<(total + 255) / 256, 256, 0, stream>>>(
        (const float4*)x0, (const float4*)x1, W, (float4*)d_out, total);
}